// Round 11
// baseline (342.488 us; speedup 1.0000x reference)
//
#include <hip/hip_runtime.h>
#include <hip/hip_bf16.h>

// MultiAgentGRULoop round 11: R6 + in-wave x-overlap + T2 swizzle + T5 setprio.
//   - 256 blocks x 512 thr (8 waves), 1 block/CU, bounds(512,1) — the only
//     envelope that doesn't spill the 96-reg weight set (R5/R7/R8 lessons).
//   - x-GEMM pipelined one step ahead IN-WAVE: gA(t) carried in 12 regs;
//     cell t = h-MFMA(t) -> epilogue(t) [uses gA] -> x-MFMA(t+1) [refills gA,
//     interleaves with epilogue VALU on the scheduler] -> staging -> barrier.
//     x lives in a 4-slot LDS ring staged two steps ahead (lean R7: +12 regs,
//     not +40 -> no spill).
//   - T2 swizzle: LSTR=128 (pow2) + slot XOR (row&7) on s_x/s_h, same
//     involution on reads, h-writes, and staging writes (rule #21).
//   - T5: setprio(1) around both MFMA clusters.
//   - Arithmetic bit-identical to R6 (swapped-operand MFMA D[gate][row],
//     f32 register h recurrence, biases in C-init, masked h, unmasked acts).

#define T_STEPS 64
#define HID 128
#define NL 3
#define RB 16
#define NTHR 512
#define NBLK 256
#define LSTR 128   // bf16 x/h row stride (shorts), power-of-2 for XOR swizzle
#define ASTR 132   // f32 act row stride (unswizzled, as R6)

typedef __attribute__((ext_vector_type(8))) short bf16x8;
typedef __attribute__((ext_vector_type(4))) short short4v;
typedef __attribute__((ext_vector_type(4))) float f32x4;

static __device__ __forceinline__ short f2bf_s(float f) {
  __hip_bfloat16 b = __float2bfloat16(f);
  return __builtin_bit_cast(short, b);
}
__device__ __forceinline__ float sigm(float v) { return 1.f / (1.f + __expf(-v)); }
__device__ __forceinline__ float tanh_f(float v) { return 1.f - 2.f / (__expf(2.f * v) + 1.f); }
// swizzled short-address within a [row][LSTR] tile; scol is 4-short aligned
__device__ __forceinline__ int swz(int row, int scol) {
  return row * LSTR + ((((scol >> 3) ^ (row & 7)) << 3) | (scol & 7));
}

#define MFMA(A, B, C) __builtin_amdgcn_mfma_f32_16x16x32_bf16((A), (B), (C), 0, 0, 0)

__global__ __launch_bounds__(NTHR, 1) void gru11(
    const float* __restrict__ x, const int* __restrict__ invalid,
    const float* __restrict__ w_ih, const float* __restrict__ w_hh,
    const float* __restrict__ b_ih, const float* __restrict__ b_hh,
    float* out)
{
  __shared__ short s_x[4][RB * LSTR];    // x bf16 4-slot ring (slot = t&3)
  __shared__ short s_h[2][RB * LSTR];    // h bf16 (masked), dbuf, swizzled
  __shared__ float s_act[2][RB * ASTR];  // f32 act staging, dbuf (as R6)
  __shared__ int   s_msk[T_STEPS * RB];  // mask, t-major

  const int tid = threadIdx.x;
  const int wave = tid >> 6, lane = tid & 63;
  const int lr = lane & 15, lq = lane >> 4;
  const int row_base = (int)blockIdx.x * RB;
  const int srow = tid >> 5, scol = (tid & 31) * 4;  // coalesced 4-elem map
  const int cb = wave * 16 + lq * 4;                 // epilogue col base

  for (int i = tid; i < T_STEPS * RB; i += NTHR) {
    const int t = i >> 4, r = i & 15;
    s_msk[i] = invalid[(size_t)(row_base + r) * T_STEPS + t];
  }

  for (int l = 0; l < NL; ++l) {
    const bool last = (l == NL - 1);
    // ---- per layer: weights -> bf16 register fragments ----
    bf16x8 wI[3][4], wH[3][4];
#pragma unroll
    for (int g = 0; g < 3; ++g)
#pragma unroll
      for (int kf = 0; kf < 4; ++kf) {
        const int wrow = g * HID + wave * 16 + lr;
        const int kofs = kf * 32 + lq * 8;
        const float* pI = w_ih + ((size_t)l * 3 * HID + wrow) * HID + kofs;
        const float* pH = w_hh + ((size_t)l * 3 * HID + wrow) * HID + kofs;
        float4 a = *(const float4*)pI, b = *(const float4*)(pI + 4);
        float vi[8] = {a.x, a.y, a.z, a.w, b.x, b.y, b.z, b.w};
        float4 c = *(const float4*)pH, d = *(const float4*)(pH + 4);
        float vh[8] = {c.x, c.y, c.z, c.w, d.x, d.y, d.z, d.w};
#pragma unroll
        for (int j = 0; j < 8; ++j) {
          wI[g][kf][j] = f2bf_s(vi[j]);
          wH[g][kf][j] = f2bf_s(vh[j]);
        }
      }
    float bRZ0[4], bRZ1[4], bNi[4], bNh[4];
#pragma unroll
    for (int ri = 0; ri < 4; ++ri) {
      const int c = cb + ri;
      const size_t base = (size_t)l * 3 * HID;
      bRZ0[ri] = b_ih[base + c] + b_hh[base + c];
      bRZ1[ri] = b_ih[base + HID + c] + b_hh[base + HID + c];
      bNi[ri]  = b_ih[base + 2 * HID + c];
      bNh[ri]  = b_hh[base + 2 * HID + c];
    }

    // ---- hoisted per-thread global pointers (staging map) ----
    const size_t soff = (size_t)(row_base + srow) * T_STEPS * HID + scol;
    const float* srcf = ((l == 0) ? x : (const float*)out) + soff;
    float* outf = out + soff;

    // ---- h := 0; stage x(0)->ring0, x(1)->ring1 ----
    for (int i = tid; i < RB * LSTR; i += NTHR) s_h[0][i] = 0;
#pragma unroll
    for (int st = 0; st < 2; ++st) {
      float4 v = *(const float4*)(srcf + (size_t)st * HID);
      short4v c4 = {f2bf_s(v.x), f2bf_s(v.y), f2bf_s(v.z), f2bf_s(v.w)};
      *(short4v*)&s_x[st][swz(srow, scol)] = c4;
    }
    __syncthreads();

    // ---- prologue: gA(0) from ring0 ----
    f32x4 gA0 = {bRZ0[0], bRZ0[1], bRZ0[2], bRZ0[3]};
    f32x4 gA1 = {bRZ1[0], bRZ1[1], bRZ1[2], bRZ1[3]};
    f32x4 gAn = {bNi[0], bNi[1], bNi[2], bNi[3]};
#pragma unroll
    for (int kf = 0; kf < 4; ++kf) {
      bf16x8 xh = *(const bf16x8*)&s_x[0][swz(lr, kf * 32 + lq * 8)];
      gA0 = MFMA(wI[0][kf], xh, gA0);
      gA1 = MFMA(wI[1][kf], xh, gA1);
      gAn = MFMA(wI[2][kf], xh, gAn);
    }
    float hprev[4] = {0.f, 0.f, 0.f, 0.f};

#pragma unroll 4
    for (int t = 0; t < T_STEPS; ++t) {
      const int p = t & 1;
      // ---- issue global load x(t+2) (consumed at staging below) ----
      float4 pin;
      if (t < T_STEPS - 2)
        pin = *(const float4*)(srcf + (size_t)(t + 2) * HID);
      // ---- deferred out-store of act(t-1) (stays in flight) ----
      if (t > 0) {
        float4 a = *(const float4*)&s_act[p][srow * ASTR + scol];
        *(float4*)(outf + (size_t)(t - 1) * HID) = a;
      }
      const int mk = s_msk[t * RB + lr];

      // ---- h-side MFMAs (the only barrier-dependent ones) ----
      f32x4 aH0 = (f32x4)(0.f), aH1 = (f32x4)(0.f);
      f32x4 aHn = {bNh[0], bNh[1], bNh[2], bNh[3]};
      __builtin_amdgcn_s_setprio(1);
#pragma unroll
      for (int kf = 0; kf < 4; ++kf) {
        bf16x8 hh = *(const bf16x8*)&s_h[p][swz(lr, kf * 32 + lq * 8)];
        aH0 = MFMA(wH[0][kf], hh, aH0);
        aH1 = MFMA(wH[1][kf], hh, aH1);
        aHn = MFMA(wH[2][kf], hh, aHn);
      }
      __builtin_amdgcn_s_setprio(0);

      // ---- epilogue (consumes gA of step t) ----
      float4 actf;
      short4v hb;
#pragma unroll
      for (int ri = 0; ri < 4; ++ri) {
        float rr = sigm(gA0[ri] + aH0[ri]);
        float zz = sigm(gA1[ri] + aH1[ri]);
        float nn = tanh_f(gAn[ri] + rr * aHn[ri]);
        float hn = nn + zz * (hprev[ri] - nn);
        float hm = mk ? 0.f : hn;
        hprev[ri] = hm;
        ((float*)&actf)[ri] = last ? hm : hn;  // y masked; inter-layer unmasked
        hb[ri] = f2bf_s(hm);
      }

      // ---- x-side MFMAs for t+1 (independent of epilogue; interleaves) ----
      if (t < T_STEPS - 1) {
        const int q1 = (t + 1) & 3;
        f32x4 n0 = {bRZ0[0], bRZ0[1], bRZ0[2], bRZ0[3]};
        f32x4 n1 = {bRZ1[0], bRZ1[1], bRZ1[2], bRZ1[3]};
        f32x4 nn = {bNi[0], bNi[1], bNi[2], bNi[3]};
        __builtin_amdgcn_s_setprio(1);
#pragma unroll
        for (int kf = 0; kf < 4; ++kf) {
          bf16x8 xh = *(const bf16x8*)&s_x[q1][swz(lr, kf * 32 + lq * 8)];
          n0 = MFMA(wI[0][kf], xh, n0);
          n1 = MFMA(wI[1][kf], xh, n1);
          nn = MFMA(wI[2][kf], xh, nn);
        }
        __builtin_amdgcn_s_setprio(0);
        gA0 = n0; gA1 = n1; gAn = nn;
      }

      // ---- LDS writes: h (swizzled), act, x-stage (swizzled) ----
      *(short4v*)&s_h[p ^ 1][swz(lr, cb)] = hb;
      *(float4*)&s_act[p ^ 1][lr * ASTR + cb] = actf;
      if (t < T_STEPS - 2) {
        short4v c4 = {f2bf_s(pin.x), f2bf_s(pin.y), f2bf_s(pin.z), f2bf_s(pin.w)};
        *(short4v*)&s_x[(t + 2) & 3][swz(srow, scol)] = c4;
      }
      // ---- LDS-only sync; globals stay in flight ----
      asm volatile("s_waitcnt lgkmcnt(0)" ::: "memory");
      __builtin_amdgcn_s_barrier();
    }
    // ---- flush act(63) (lives in buffer 0) ----
    {
      float4 a = *(const float4*)&s_act[0][srow * ASTR + scol];
      *(float4*)(outf + (size_t)(T_STEPS - 1) * HID) = a;
    }
    __syncthreads();  // full drain: out visible before next layer stages from it
  }
}

extern "C" void kernel_launch(void* const* d_in, const int* in_sizes, int n_in,
                              void* d_out, int out_size, void* d_ws, size_t ws_size,
                              hipStream_t stream) {
  const float* x       = (const float*)d_in[0];
  const int*   invalid = (const int*)d_in[1];
  const float* w_ih    = (const float*)d_in[2];
  const float* w_hh    = (const float*)d_in[3];
  const float* b_ih    = (const float*)d_in[4];
  const float* b_hh    = (const float*)d_in[5];
  gru11<<<dim3(NBLK), dim3(NTHR), 0, stream>>>(x, invalid, w_ih, w_hh, b_ih, b_hh,
                                               (float*)d_out);
}

// Round 12
// 279.535 us; speedup vs baseline: 1.2252x; 1.2252x over previous
//
#include <hip/hip_runtime.h>
#include <hip/hip_bf16.h>

// MultiAgentGRULoop round 12: R6 minus the s_act round-trip and mask ds_reads.
//   - 256 blocks x 512 thr (8 waves), 1 block/CU, bounds(512,1) — R6 envelope.
//   - Epilogue stores act DIRECTLY to global: lanes lq=0..3 of a row write 4
//     consecutive 16B chunks = one aligned 64B line per (row,wave) -> no
//     write amplification, and the s_act LDS round-trip (R11 diagnostic: the
//     real bank-conflict source) disappears.
//   - invalid mask packed into 2 u32 registers/thread via __ballot (built
//     once); per-cell mask = bit test, not a ds_read on the lgkm chain.
//   - Everything else EXACTLY R6: swapped-operand MFMA D[gate][row], bf16
//     frags with k-map kf*32+lq*8, f32 register h recurrence, biases in
//     C-init, lgkmcnt-only per-cell barrier, x prefetch t+1, LSTR=136.

#define T_STEPS 64
#define HID 128
#define NL 3
#define RB 16
#define NTHR 512
#define NBLK 256
#define LSTR 136   // bf16 x/h row stride (shorts): 272 B, 16B-aligned

typedef __attribute__((ext_vector_type(8))) short bf16x8;
typedef __attribute__((ext_vector_type(4))) short short4v;
typedef __attribute__((ext_vector_type(4))) float f32x4;

static __device__ __forceinline__ short f2bf_s(float f) {
  __hip_bfloat16 b = __float2bfloat16(f);
  return __builtin_bit_cast(short, b);
}
__device__ __forceinline__ float sigm(float v) { return 1.f / (1.f + __expf(-v)); }
__device__ __forceinline__ float tanh_f(float v) { return 1.f - 2.f / (__expf(2.f * v) + 1.f); }

#define MFMA(A, B, C) __builtin_amdgcn_mfma_f32_16x16x32_bf16((A), (B), (C), 0, 0, 0)

__global__ __launch_bounds__(NTHR, 1) void gru12(
    const float* __restrict__ x, const int* __restrict__ invalid,
    const float* __restrict__ w_ih, const float* __restrict__ w_hh,
    const float* __restrict__ b_ih, const float* __restrict__ b_hh,
    float* out)
{
  __shared__ short s_x[2][RB * LSTR];  // input bf16 (x[t], x[t+1])
  __shared__ short s_h[2][RB * LSTR];  // h bf16 (masked), dbuf
  __shared__ unsigned s_mw[RB * 2];    // packed masks: [row][word], built once

  const int tid = threadIdx.x;
  const int wave = tid >> 6, lane = tid & 63;
  const int lr = lane & 15, lq = lane >> 4;
  const int row_base = (int)blockIdx.x * RB;
  const int srow = tid >> 5, scol = (tid & 31) * 4;  // coalesced f32x4 map
  const int cb = wave * 16 + lq * 4;                 // epilogue col base

  // ---- pack invalid -> 2 u32 words per row via ballot (once) ----
  {
    const int rr = 2 * wave + (lane >> 5);
    const int tt = lane & 31;
    const size_t base = (size_t)(row_base + rr) * T_STEPS;
    unsigned long long b1 = __ballot(invalid[base + tt] != 0);
    unsigned long long b2 = __ballot(invalid[base + 32 + tt] != 0);
    if (lane == 0) {
      s_mw[(2 * wave) * 2]     = (unsigned)b1;
      s_mw[(2 * wave + 1) * 2] = (unsigned)(b1 >> 32);
      s_mw[(2 * wave) * 2 + 1]     = (unsigned)b2;
      s_mw[(2 * wave + 1) * 2 + 1] = (unsigned)(b2 >> 32);
    }
  }
  __syncthreads();
  const unsigned mw0 = s_mw[lr * 2], mw1 = s_mw[lr * 2 + 1];

  for (int l = 0; l < NL; ++l) {
    const bool last = (l == NL - 1);
    // ---- per layer: weights -> bf16 register fragments ----
    bf16x8 wI[3][4], wH[3][4];
#pragma unroll
    for (int g = 0; g < 3; ++g)
#pragma unroll
      for (int kf = 0; kf < 4; ++kf) {
        const int wrow = g * HID + wave * 16 + lr;
        const int kofs = kf * 32 + lq * 8;
        const float* pI = w_ih + ((size_t)l * 3 * HID + wrow) * HID + kofs;
        const float* pH = w_hh + ((size_t)l * 3 * HID + wrow) * HID + kofs;
        float4 a = *(const float4*)pI, b = *(const float4*)(pI + 4);
        float vi[8] = {a.x, a.y, a.z, a.w, b.x, b.y, b.z, b.w};
        float4 c = *(const float4*)pH, d = *(const float4*)(pH + 4);
        float vh[8] = {c.x, c.y, c.z, c.w, d.x, d.y, d.z, d.w};
#pragma unroll
        for (int j = 0; j < 8; ++j) {
          wI[g][kf][j] = f2bf_s(vi[j]);
          wH[g][kf][j] = f2bf_s(vh[j]);
        }
      }
    float bRZ0[4], bRZ1[4], bNi[4], bNh[4];
#pragma unroll
    for (int ri = 0; ri < 4; ++ri) {
      const int c = cb + ri;
      const size_t base = (size_t)l * 3 * HID;
      bRZ0[ri] = b_ih[base + c] + b_hh[base + c];
      bRZ1[ri] = b_ih[base + HID + c] + b_hh[base + HID + c];
      bNi[ri]  = b_ih[base + 2 * HID + c];
      bNh[ri]  = b_hh[base + 2 * HID + c];
    }

    // ---- hoisted per-thread global pointers ----
    const float* srcf = ((l == 0) ? x : (const float*)out) +
                        (size_t)(row_base + srow) * T_STEPS * HID + scol;   // staging map
    float* outsc = out + (size_t)(row_base + lr) * T_STEPS * HID + cb;      // scatter map

    // ---- h := 0, stage input[t=0] into buffer 0 ----
    for (int i = tid; i < RB * LSTR; i += NTHR) s_h[0][i] = 0;
    {
      float4 v = *(const float4*)srcf;
      short4v c4 = {f2bf_s(v.x), f2bf_s(v.y), f2bf_s(v.z), f2bf_s(v.w)};
      *(short4v*)&s_x[0][srow * LSTR + scol] = c4;
    }
    float hprev[4] = {0.f, 0.f, 0.f, 0.f};
    __syncthreads();

    for (int t = 0; t < T_STEPS; ++t) {
      const int p = t & 1;
      // ---- prefetch next-step input (consumed at staging, end of cell) ----
      float4 pin;
      if (t < T_STEPS - 1)
        pin = *(const float4*)(srcf + (size_t)(t + 1) * HID);
      const int mk = (int)((((t & 32) ? mw1 : mw0) >> (t & 31)) & 1u);

      // ---- MFMA phase, swapped operands: D[gate_col][act_row] ----
      f32x4 aI0 = {bRZ0[0], bRZ0[1], bRZ0[2], bRZ0[3]};
      f32x4 aH0 = (f32x4)(0.f);
      f32x4 aI1 = {bRZ1[0], bRZ1[1], bRZ1[2], bRZ1[3]};
      f32x4 aH1 = (f32x4)(0.f);
      f32x4 aN  = {bNi[0], bNi[1], bNi[2], bNi[3]};
      f32x4 aHn = {bNh[0], bNh[1], bNh[2], bNh[3]};
#pragma unroll
      for (int kf = 0; kf < 4; ++kf) {
        const int ao = lr * LSTR + kf * 32 + lq * 8;
        bf16x8 xh = *(const bf16x8*)&s_x[p][ao];
        bf16x8 hh = *(const bf16x8*)&s_h[p][ao];
        aI0 = MFMA(wI[0][kf], xh, aI0);
        aH0 = MFMA(wH[0][kf], hh, aH0);
        aI1 = MFMA(wI[1][kf], xh, aI1);
        aH1 = MFMA(wH[1][kf], hh, aH1);
        aN  = MFMA(wI[2][kf], xh, aN);
        aHn = MFMA(wH[2][kf], hh, aHn);
      }

      // ---- epilogue: lane owns act row lr, gate cols cb..cb+3 ----
      float4 actf;
      short4v hb;
#pragma unroll
      for (int ri = 0; ri < 4; ++ri) {
        float rr = sigm(aI0[ri] + aH0[ri]);
        float zz = sigm(aI1[ri] + aH1[ri]);
        float nn = tanh_f(aN[ri] + rr * aHn[ri]);
        float hn = nn + zz * (hprev[ri] - nn);
        float hm = mk ? 0.f : hn;
        hprev[ri] = hm;
        ((float*)&actf)[ri] = last ? hm : hn;  // y masked; inter-layer unmasked
        hb[ri] = f2bf_s(hm);
      }
      // direct global store: 4 lanes/row tile one aligned 64B line
      *(float4*)(outsc + (size_t)t * HID) = actf;
      *(short4v*)&s_h[p ^ 1][lr * LSTR + cb] = hb;

      if (t < T_STEPS - 1) {
        short4v c4 = {f2bf_s(pin.x), f2bf_s(pin.y), f2bf_s(pin.z), f2bf_s(pin.w)};
        *(short4v*)&s_x[p ^ 1][srow * LSTR + scol] = c4;
      }
      // ---- LDS-only sync; globals stay in flight ----
      asm volatile("s_waitcnt lgkmcnt(0)" ::: "memory");
      __builtin_amdgcn_s_barrier();
    }
    __syncthreads();  // full drain: out visible before next layer stages from it
  }
}

extern "C" void kernel_launch(void* const* d_in, const int* in_sizes, int n_in,
                              void* d_out, int out_size, void* d_ws, size_t ws_size,
                              hipStream_t stream) {
  const float* x       = (const float*)d_in[0];
  const int*   invalid = (const int*)d_in[1];
  const float* w_ih    = (const float*)d_in[2];
  const float* w_hh    = (const float*)d_in[3];
  const float* b_ih    = (const float*)d_in[4];
  const float* b_hh    = (const float*)d_in[5];
  gru12<<<dim3(NBLK), dim3(NTHR), 0, stream>>>(x, invalid, w_ih, w_hh, b_ih, b_hh,
                                               (float*)d_out);
}

// Round 13
// 216.506 us; speedup vs baseline: 1.5819x; 1.2911x over previous
//
#include <hip/hip_runtime.h>
#include <hip/hip_bf16.h>

// MultiAgentGRULoop round 13: R12 structure + VALU diet.
//   - v_rcp_f32 (asm) replaces 3 full-precision f32 divides/element (~10
//     inst each without fast-math) — the round-12 VALU mystery.
//   - exp2 folding: Wr,Wz,brz scaled by -log2e; Wn_i,Wn_h,bn by 2*log2e at
//     weight load (r unscaled, multiplies only scaled terms — exact algebra).
//     sigmoid = rcp(1+exp2(s)); tanh = fma(-2, rcp(e+1), 1).
//   - bf16 inter-layer acts in d_ws, layer-static code (template<SRCBF,LASTL>,
//     three inlined calls, ONE kernel): layers 1-2 stage via pure short4 copy
//     (zero converts); act stores b64. ws >= 67MB proven by R10's run.
//   - Everything else exactly R12: 256x512, bounds(512,1), swapped-operand
//     MFMA D[gate][row], f32 register h recurrence, biases in C-init, packed
//     ballot masks, direct global act store, lgkmcnt-only per-cell barrier.

#define T_STEPS 64
#define HID 128
#define NL 3
#define RB 16
#define NTHR 512
#define NBLK 256
#define LSTR 136   // bf16 x/h row stride (shorts): 272 B, 16B-aligned

typedef __attribute__((ext_vector_type(8))) short bf16x8;
typedef __attribute__((ext_vector_type(4))) short short4v;
typedef __attribute__((ext_vector_type(4))) float f32x4;

static __device__ __forceinline__ short f2bf_s(float f) {
  __hip_bfloat16 b = __float2bfloat16(f);
  return __builtin_bit_cast(short, b);
}
static __device__ __forceinline__ float rcp_f(float x) {
  float r; asm("v_rcp_f32 %0, %1" : "=v"(r) : "v"(x)); return r;
}
static __device__ __forceinline__ float exp2_f(float x) {
  float r; asm("v_exp_f32 %0, %1" : "=v"(r) : "v"(x)); return r;
}

#define MFMA(A, B, C) __builtin_amdgcn_mfma_f32_16x16x32_bf16((A), (B), (C), 0, 0, 0)

#define NL2E  (-1.4426950408889634f)   // -log2(e)
#define T2L2E (2.8853900817779268f)    // 2*log2(e)

template <bool SRCBF, bool LASTL>
__device__ __forceinline__ void layer_pass(
    const float* __restrict__ wih, const float* __restrict__ whh,
    const float* __restrict__ bih, const float* __restrict__ bhh,
    const float* srcf, const unsigned short* srcb,
    float* dstf, unsigned short* dstb,
    unsigned mw0, unsigned mw1,
    short (*s_x)[RB * LSTR], short (*s_h)[RB * LSTR],
    int tid, int wave, int lr, int lq, int srow, int scol, int cb)
{
  // ---- weights -> bf16 register fragments, exp2 scaling folded in ----
  bf16x8 wI[3][4], wH[3][4];
#pragma unroll
  for (int g = 0; g < 3; ++g) {
    const float sc = (g < 2) ? NL2E : T2L2E;
#pragma unroll
    for (int kf = 0; kf < 4; ++kf) {
      const int wrow = g * HID + wave * 16 + lr;
      const int kofs = kf * 32 + lq * 8;
      const float* pI = wih + (size_t)wrow * HID + kofs;
      const float* pH = whh + (size_t)wrow * HID + kofs;
      float4 a = *(const float4*)pI, b = *(const float4*)(pI + 4);
      float vi[8] = {a.x, a.y, a.z, a.w, b.x, b.y, b.z, b.w};
      float4 c = *(const float4*)pH, d = *(const float4*)(pH + 4);
      float vh[8] = {c.x, c.y, c.z, c.w, d.x, d.y, d.z, d.w};
#pragma unroll
      for (int j = 0; j < 8; ++j) {
        wI[g][kf][j] = f2bf_s(sc * vi[j]);
        wH[g][kf][j] = f2bf_s(sc * vh[j]);
      }
    }
  }
  f32x4 bRZ0v, bRZ1v, bNiv, bNhv;
#pragma unroll
  for (int ri = 0; ri < 4; ++ri) {
    const int c = cb + ri;
    bRZ0v[ri] = NL2E * (bih[c] + bhh[c]);
    bRZ1v[ri] = NL2E * (bih[HID + c] + bhh[HID + c]);
    bNiv[ri]  = T2L2E * bih[2 * HID + c];
    bNhv[ri]  = T2L2E * bhh[2 * HID + c];
  }

  // ---- h := 0, stage input[t=0] into buffer 0 ----
  for (int i = tid; i < RB * LSTR; i += NTHR) s_h[0][i] = 0;
  if (SRCBF) {
    *(short4v*)&s_x[0][srow * LSTR + scol] = *(const short4v*)srcb;
  } else {
    float4 v = *(const float4*)srcf;
    short4v c4 = {f2bf_s(v.x), f2bf_s(v.y), f2bf_s(v.z), f2bf_s(v.w)};
    *(short4v*)&s_x[0][srow * LSTR + scol] = c4;
  }
  float hprev[4] = {0.f, 0.f, 0.f, 0.f};
  __syncthreads();

  for (int t = 0; t < T_STEPS; ++t) {
    const int p = t & 1;
    // ---- prefetch next-step input (consumed at staging, end of cell) ----
    float4 pinf;
    short4v pinb;
    if (t < T_STEPS - 1) {
      if (SRCBF) pinb = *(const short4v*)(srcb + (size_t)(t + 1) * HID);
      else       pinf = *(const float4*)(srcf + (size_t)(t + 1) * HID);
    }
    const int mk = (int)((((t & 32) ? mw1 : mw0) >> (t & 31)) & 1u);

    // ---- MFMA phase, swapped operands: D[gate_col][act_row] ----
    f32x4 aI0 = bRZ0v, aH0 = (f32x4)(0.f);
    f32x4 aI1 = bRZ1v, aH1 = (f32x4)(0.f);
    f32x4 aN = bNiv, aHn = bNhv;
#pragma unroll
    for (int kf = 0; kf < 4; ++kf) {
      const int ao = lr * LSTR + kf * 32 + lq * 8;
      bf16x8 xh = *(const bf16x8*)&s_x[p][ao];
      bf16x8 hh = *(const bf16x8*)&s_h[p][ao];
      aI0 = MFMA(wI[0][kf], xh, aI0);
      aH0 = MFMA(wH[0][kf], hh, aH0);
      aI1 = MFMA(wI[1][kf], xh, aI1);
      aH1 = MFMA(wH[1][kf], hh, aH1);
      aN  = MFMA(wI[2][kf], xh, aN);
      aHn = MFMA(wH[2][kf], hh, aHn);
    }

    // ---- epilogue: lane owns act row lr, gate cols cb..cb+3 ----
    float4 actf;
    short4v ab, hb;
#pragma unroll
    for (int ri = 0; ri < 4; ++ri) {
      float rr = rcp_f(1.f + exp2_f(aI0[ri] + aH0[ri]));   // sigmoid (folded)
      float zz = rcp_f(1.f + exp2_f(aI1[ri] + aH1[ri]));
      float en = exp2_f(fmaf(rr, aHn[ri], aN[ri]));        // 2^(2*log2e*u)
      float nn = fmaf(-2.f, rcp_f(en + 1.f), 1.f);         // tanh(u)
      float hn = fmaf(zz, hprev[ri] - nn, nn);
      float hm = mk ? 0.f : hn;
      hprev[ri] = hm;
      short bf = f2bf_s(hn);
      hb[ri] = mk ? (short)0 : bf;
      if (LASTL) ((float*)&actf)[ri] = hm;  // masked y
      else       ab[ri] = bf;               // unmasked bf16 act
    }
    if (LASTL) *(float4*)(dstf + (size_t)t * HID) = actf;
    else       *(short4v*)(dstb + (size_t)t * HID) = ab;
    *(short4v*)&s_h[p ^ 1][lr * LSTR + cb] = hb;

    if (t < T_STEPS - 1) {
      if (SRCBF) {
        *(short4v*)&s_x[p ^ 1][srow * LSTR + scol] = pinb;
      } else {
        short4v c4 = {f2bf_s(pinf.x), f2bf_s(pinf.y), f2bf_s(pinf.z), f2bf_s(pinf.w)};
        *(short4v*)&s_x[p ^ 1][srow * LSTR + scol] = c4;
      }
    }
    // ---- LDS-only sync; globals stay in flight ----
    asm volatile("s_waitcnt lgkmcnt(0)" ::: "memory");
    __builtin_amdgcn_s_barrier();
  }
}

__global__ __launch_bounds__(NTHR, 1) void gru13(
    const float* __restrict__ x, const int* __restrict__ invalid,
    const float* __restrict__ w_ih, const float* __restrict__ w_hh,
    const float* __restrict__ b_ih, const float* __restrict__ b_hh,
    float* out, unsigned short* ws)
{
  __shared__ short s_x[2][RB * LSTR];
  __shared__ short s_h[2][RB * LSTR];
  __shared__ unsigned s_mw[RB * 2];

  const int tid = threadIdx.x;
  const int wave = tid >> 6, lane = tid & 63;
  const int lr = lane & 15, lq = lane >> 4;
  const int row_base = (int)blockIdx.x * RB;
  const int srow = tid >> 5, scol = (tid & 31) * 4;  // coalesced staging map
  const int cb = wave * 16 + lq * 4;                 // epilogue col base

  // ---- pack invalid -> 2 u32 words per row via ballot (once) ----
  {
    const int rr = 2 * wave + (lane >> 5);
    const int tt = lane & 31;
    const size_t base = (size_t)(row_base + rr) * T_STEPS;
    unsigned long long b1 = __ballot(invalid[base + tt] != 0);
    unsigned long long b2 = __ballot(invalid[base + 32 + tt] != 0);
    if (lane == 0) {
      s_mw[(2 * wave) * 2]         = (unsigned)b1;
      s_mw[(2 * wave + 1) * 2]     = (unsigned)(b1 >> 32);
      s_mw[(2 * wave) * 2 + 1]     = (unsigned)b2;
      s_mw[(2 * wave + 1) * 2 + 1] = (unsigned)(b2 >> 32);
    }
  }
  __syncthreads();
  const unsigned mw0 = s_mw[lr * 2], mw1 = s_mw[lr * 2 + 1];

  const size_t soff = (size_t)(row_base + srow) * T_STEPS * HID + scol;  // staging
  const size_t doff = (size_t)(row_base + lr) * T_STEPS * HID + cb;      // scatter

  // L0: f32 x -> bf16 ws (unmasked acts)
  layer_pass<false, false>(w_ih, w_hh, b_ih, b_hh,
                           x + soff, nullptr, nullptr, ws + doff,
                           mw0, mw1, s_x, s_h, tid, wave, lr, lq, srow, scol, cb);
  __syncthreads();  // full drain: ws visible before L1 stages it
  // L1: bf16 ws -> bf16 ws (in-place per (row,t); write(t) is >1 cell after read(t))
  layer_pass<true, false>(w_ih + 3 * HID * HID, w_hh + 3 * HID * HID,
                          b_ih + 3 * HID, b_hh + 3 * HID,
                          nullptr, ws + soff, nullptr, ws + doff,
                          mw0, mw1, s_x, s_h, tid, wave, lr, lq, srow, scol, cb);
  __syncthreads();
  // L2: bf16 ws -> f32 out (masked y)
  layer_pass<true, true>(w_ih + 6 * HID * HID, w_hh + 6 * HID * HID,
                         b_ih + 6 * HID, b_hh + 6 * HID,
                         nullptr, ws + soff, out + doff, nullptr,
                         mw0, mw1, s_x, s_h, tid, wave, lr, lq, srow, scol, cb);
}

extern "C" void kernel_launch(void* const* d_in, const int* in_sizes, int n_in,
                              void* d_out, int out_size, void* d_ws, size_t ws_size,
                              hipStream_t stream) {
  const float* x       = (const float*)d_in[0];
  const int*   invalid = (const int*)d_in[1];
  const float* w_ih    = (const float*)d_in[2];
  const float* w_hh    = (const float*)d_in[3];
  const float* b_ih    = (const float*)d_in[4];
  const float* b_hh    = (const float*)d_in[5];
  // ws requirement: 4096*64*128 bf16 = 64 MiB. R10's run confirmed ws_size
  // covers this on this harness (its >=need branch was taken).
  gru13<<<dim3(NBLK), dim3(NTHR), 0, stream>>>(x, invalid, w_ih, w_hh, b_ih, b_hh,
                                               (float*)d_out, (unsigned short*)d_ws);
}

// Round 14
// 214.120 us; speedup vs baseline: 1.5995x; 1.0111x over previous
//
#include <hip/hip_runtime.h>
#include <hip/hip_bf16.h>

// MultiAgentGRULoop round 14: R13 + in-wave x-MFMA pipeline (one step ahead).
//   - Cell t: h-MFMA(t) [12, barrier-dependent] -> epilogue(t) using gA(t)
//     carried in regs  ||  x-MFMA(t+1) [12, independent -> scheduler
//     interleaves with the epilogue trans chain] -> writes -> lgkm barrier.
//   - x staged in a 4-slot LDS ring two steps ahead (pin = x(t+2) issued at
//     cell top, staged at cell end). +~30 regs vs R13; cap is 256 (8 w/CU).
//   - ALL else byte-identical to R13: rcp/exp2 epilogue, folded gate scaling,
//     bf16 inter-layer acts in d_ws (template<SRCBF,LASTL>), packed ballot
//     masks, direct global act stores, LSTR=136, lgkmcnt-only barrier.

#define T_STEPS 64
#define HID 128
#define NL 3
#define RB 16
#define NTHR 512
#define NBLK 256
#define LSTR 136   // bf16 x/h row stride (shorts): 272 B, 16B-aligned

typedef __attribute__((ext_vector_type(8))) short bf16x8;
typedef __attribute__((ext_vector_type(4))) short short4v;
typedef __attribute__((ext_vector_type(4))) float f32x4;

static __device__ __forceinline__ short f2bf_s(float f) {
  __hip_bfloat16 b = __float2bfloat16(f);
  return __builtin_bit_cast(short, b);
}
static __device__ __forceinline__ float rcp_f(float x) {
  float r; asm("v_rcp_f32 %0, %1" : "=v"(r) : "v"(x)); return r;
}
static __device__ __forceinline__ float exp2_f(float x) {
  float r; asm("v_exp_f32 %0, %1" : "=v"(r) : "v"(x)); return r;
}

#define MFMA(A, B, C) __builtin_amdgcn_mfma_f32_16x16x32_bf16((A), (B), (C), 0, 0, 0)

#define NL2E  (-1.4426950408889634f)   // -log2(e)
#define T2L2E (2.8853900817779268f)    // 2*log2(e)

template <bool SRCBF, bool LASTL>
__device__ __forceinline__ void layer_pass(
    const float* __restrict__ wih, const float* __restrict__ whh,
    const float* __restrict__ bih, const float* __restrict__ bhh,
    const float* srcf, const unsigned short* srcb,
    float* dstf, unsigned short* dstb,
    unsigned mw0, unsigned mw1,
    short (*s_x)[RB * LSTR], short (*s_h)[RB * LSTR],
    int tid, int wave, int lr, int lq, int srow, int scol, int cb)
{
  // ---- weights -> bf16 register fragments, exp2 scaling folded in ----
  bf16x8 wI[3][4], wH[3][4];
#pragma unroll
  for (int g = 0; g < 3; ++g) {
    const float sc = (g < 2) ? NL2E : T2L2E;
#pragma unroll
    for (int kf = 0; kf < 4; ++kf) {
      const int wrow = g * HID + wave * 16 + lr;
      const int kofs = kf * 32 + lq * 8;
      const float* pI = wih + (size_t)wrow * HID + kofs;
      const float* pH = whh + (size_t)wrow * HID + kofs;
      float4 a = *(const float4*)pI, b = *(const float4*)(pI + 4);
      float vi[8] = {a.x, a.y, a.z, a.w, b.x, b.y, b.z, b.w};
      float4 c = *(const float4*)pH, d = *(const float4*)(pH + 4);
      float vh[8] = {c.x, c.y, c.z, c.w, d.x, d.y, d.z, d.w};
#pragma unroll
      for (int j = 0; j < 8; ++j) {
        wI[g][kf][j] = f2bf_s(sc * vi[j]);
        wH[g][kf][j] = f2bf_s(sc * vh[j]);
      }
    }
  }
  f32x4 bRZ0v, bRZ1v, bNiv, bNhv;
#pragma unroll
  for (int ri = 0; ri < 4; ++ri) {
    const int c = cb + ri;
    bRZ0v[ri] = NL2E * (bih[c] + bhh[c]);
    bRZ1v[ri] = NL2E * (bih[HID + c] + bhh[HID + c]);
    bNiv[ri]  = T2L2E * bih[2 * HID + c];
    bNhv[ri]  = T2L2E * bhh[2 * HID + c];
  }

  // ---- h := 0; stage x(0)->slot0, x(1)->slot1 ----
  for (int i = tid; i < RB * LSTR; i += NTHR) s_h[0][i] = 0;
#pragma unroll
  for (int st = 0; st < 2; ++st) {
    if (SRCBF) {
      *(short4v*)&s_x[st][srow * LSTR + scol] = *(const short4v*)(srcb + (size_t)st * HID);
    } else {
      float4 v = *(const float4*)(srcf + (size_t)st * HID);
      short4v c4 = {f2bf_s(v.x), f2bf_s(v.y), f2bf_s(v.z), f2bf_s(v.w)};
      *(short4v*)&s_x[st][srow * LSTR + scol] = c4;
    }
  }
  __syncthreads();

  // ---- prologue: gA(0) from slot 0 ----
  f32x4 gA0 = bRZ0v, gA1 = bRZ1v, gAn = bNiv;
#pragma unroll
  for (int kf = 0; kf < 4; ++kf) {
    bf16x8 xh = *(const bf16x8*)&s_x[0][lr * LSTR + kf * 32 + lq * 8];
    gA0 = MFMA(wI[0][kf], xh, gA0);
    gA1 = MFMA(wI[1][kf], xh, gA1);
    gAn = MFMA(wI[2][kf], xh, gAn);
  }
  float hprev[4] = {0.f, 0.f, 0.f, 0.f};

  for (int t = 0; t < T_STEPS; ++t) {
    const int p = t & 1;
    // ---- issue x(t+2) load (consumed at staging, end of cell) ----
    float4 pinf;
    short4v pinb;
    if (t < T_STEPS - 2) {
      if (SRCBF) pinb = *(const short4v*)(srcb + (size_t)(t + 2) * HID);
      else       pinf = *(const float4*)(srcf + (size_t)(t + 2) * HID);
    }
    const int mk = (int)((((t & 32) ? mw1 : mw0) >> (t & 31)) & 1u);

    // ---- h-side MFMAs (the only barrier-dependent ones) ----
    f32x4 aH0 = (f32x4)(0.f), aH1 = (f32x4)(0.f), aHn = bNhv;
#pragma unroll
    for (int kf = 0; kf < 4; ++kf) {
      bf16x8 hh = *(const bf16x8*)&s_h[p][lr * LSTR + kf * 32 + lq * 8];
      aH0 = MFMA(wH[0][kf], hh, aH0);
      aH1 = MFMA(wH[1][kf], hh, aH1);
      aHn = MFMA(wH[2][kf], hh, aHn);
    }

    // ---- epilogue (consumes gA of step t) ----
    float4 actf;
    short4v ab, hb;
#pragma unroll
    for (int ri = 0; ri < 4; ++ri) {
      float rr = rcp_f(1.f + exp2_f(gA0[ri] + aH0[ri]));   // sigmoid (folded)
      float zz = rcp_f(1.f + exp2_f(gA1[ri] + aH1[ri]));
      float en = exp2_f(fmaf(rr, aHn[ri], gAn[ri]));       // 2^(2*log2e*u)
      float nn = fmaf(-2.f, rcp_f(en + 1.f), 1.f);         // tanh(u)
      float hn = fmaf(zz, hprev[ri] - nn, nn);
      float hm = mk ? 0.f : hn;
      hprev[ri] = hm;
      short bf = f2bf_s(hn);
      hb[ri] = mk ? (short)0 : bf;
      if (LASTL) ((float*)&actf)[ri] = hm;  // masked y
      else       ab[ri] = bf;               // unmasked bf16 act
    }

    // ---- x-side MFMAs for t+1 (independent; interleaves with epilogue) ----
    if (t < T_STEPS - 1) {
      const short* xb = &s_x[(t + 1) & 3][lr * LSTR + lq * 8];
      f32x4 n0 = bRZ0v, n1 = bRZ1v, n2 = bNiv;
#pragma unroll
      for (int kf = 0; kf < 4; ++kf) {
        bf16x8 xh = *(const bf16x8*)(xb + kf * 32);
        n0 = MFMA(wI[0][kf], xh, n0);
        n1 = MFMA(wI[1][kf], xh, n1);
        n2 = MFMA(wI[2][kf], xh, n2);
      }
      gA0 = n0; gA1 = n1; gAn = n2;
    }

    // ---- writes: act (direct global), h (LDS), x-stage (LDS ring) ----
    if (LASTL) *(float4*)(dstf + (size_t)t * HID) = actf;
    else       *(short4v*)(dstb + (size_t)t * HID) = ab;
    *(short4v*)&s_h[p ^ 1][lr * LSTR + cb] = hb;
    if (t < T_STEPS - 2) {
      if (SRCBF) {
        *(short4v*)&s_x[(t + 2) & 3][srow * LSTR + scol] = pinb;
      } else {
        short4v c4 = {f2bf_s(pinf.x), f2bf_s(pinf.y), f2bf_s(pinf.z), f2bf_s(pinf.w)};
        *(short4v*)&s_x[(t + 2) & 3][srow * LSTR + scol] = c4;
      }
    }
    // ---- LDS-only sync; globals stay in flight ----
    asm volatile("s_waitcnt lgkmcnt(0)" ::: "memory");
    __builtin_amdgcn_s_barrier();
  }
}

__global__ __launch_bounds__(NTHR, 1) void gru14(
    const float* __restrict__ x, const int* __restrict__ invalid,
    const float* __restrict__ w_ih, const float* __restrict__ w_hh,
    const float* __restrict__ b_ih, const float* __restrict__ b_hh,
    float* out, unsigned short* ws)
{
  __shared__ short s_x[4][RB * LSTR];  // x bf16 4-slot ring (slot = t&3)
  __shared__ short s_h[2][RB * LSTR];  // h bf16 (masked), dbuf
  __shared__ unsigned s_mw[RB * 2];

  const int tid = threadIdx.x;
  const int wave = tid >> 6, lane = tid & 63;
  const int lr = lane & 15, lq = lane >> 4;
  const int row_base = (int)blockIdx.x * RB;
  const int srow = tid >> 5, scol = (tid & 31) * 4;  // coalesced staging map
  const int cb = wave * 16 + lq * 4;                 // epilogue col base

  // ---- pack invalid -> 2 u32 words per row via ballot (once) ----
  {
    const int rr = 2 * wave + (lane >> 5);
    const int tt = lane & 31;
    const size_t base = (size_t)(row_base + rr) * T_STEPS;
    unsigned long long b1 = __ballot(invalid[base + tt] != 0);
    unsigned long long b2 = __ballot(invalid[base + 32 + tt] != 0);
    if (lane == 0) {
      s_mw[(2 * wave) * 2]         = (unsigned)b1;
      s_mw[(2 * wave + 1) * 2]     = (unsigned)(b1 >> 32);
      s_mw[(2 * wave) * 2 + 1]     = (unsigned)b2;
      s_mw[(2 * wave + 1) * 2 + 1] = (unsigned)(b2 >> 32);
    }
  }
  __syncthreads();
  const unsigned mw0 = s_mw[lr * 2], mw1 = s_mw[lr * 2 + 1];

  const size_t soff = (size_t)(row_base + srow) * T_STEPS * HID + scol;  // staging
  const size_t doff = (size_t)(row_base + lr) * T_STEPS * HID + cb;      // scatter

  // L0: f32 x -> bf16 ws (unmasked acts)
  layer_pass<false, false>(w_ih, w_hh, b_ih, b_hh,
                           x + soff, nullptr, nullptr, ws + doff,
                           mw0, mw1, s_x, s_h, tid, wave, lr, lq, srow, scol, cb);
  __syncthreads();  // full drain: ws visible before L1 stages it
  // L1: bf16 ws -> bf16 ws (in-place; reads lead writes by >=2 barriers)
  layer_pass<true, false>(w_ih + 3 * HID * HID, w_hh + 3 * HID * HID,
                          b_ih + 3 * HID, b_hh + 3 * HID,
                          nullptr, ws + soff, nullptr, ws + doff,
                          mw0, mw1, s_x, s_h, tid, wave, lr, lq, srow, scol, cb);
  __syncthreads();
  // L2: bf16 ws -> f32 out (masked y)
  layer_pass<true, true>(w_ih + 6 * HID * HID, w_hh + 6 * HID * HID,
                         b_ih + 6 * HID, b_hh + 6 * HID,
                         nullptr, ws + soff, out + doff, nullptr,
                         mw0, mw1, s_x, s_h, tid, wave, lr, lq, srow, scol, cb);
}

extern "C" void kernel_launch(void* const* d_in, const int* in_sizes, int n_in,
                              void* d_out, int out_size, void* d_ws, size_t ws_size,
                              hipStream_t stream) {
  const float* x       = (const float*)d_in[0];
  const int*   invalid = (const int*)d_in[1];
  const float* w_ih    = (const float*)d_in[2];
  const float* w_hh    = (const float*)d_in[3];
  const float* b_ih    = (const float*)d_in[4];
  const float* b_hh    = (const float*)d_in[5];
  gru14<<<dim3(NBLK), dim3(NTHR), 0, stream>>>(x, invalid, w_ih, w_hh, b_ih, b_hh,
                                               (float*)d_out, (unsigned short*)d_ws);
}